// Round 1
// baseline (1433.335 us; speedup 1.0000x reference)
//
#include <hip/hip_runtime.h>

#define D 492
#define KC 40
#define DECAY 0.9f
#define EPS 1e-5f

// ---------------------------------------------------------------- K0: ||e_k||^2
__global__ void vq_sqnorm(const float* __restrict__ emb, float* __restrict__ sq) {
  int k = blockIdx.x;
  int lane = threadIdx.x;
  float s = 0.f;
  for (int d = lane; d < D; d += 64) {
    float v = emb[k * D + d];
    s = fmaf(v, v, s);
  }
  #pragma unroll
  for (int off = 32; off; off >>= 1) s += __shfl_down(s, off, 64);
  if (lane == 0) sq[k] = s;
}

// ---------------------------------------------------------------- K1: argmin + counts + sumsq
// 256 rows/block (thread == row). D chunked by 56; x-tile staged in LDS
// (stride 60 floats: 16B-aligned rows, bank spread). Codebook read at
// wave-uniform addresses -> scalar (SMEM) loads, FMA with SGPR operand.
__global__ __launch_bounds__(256) void vq_assign(
    const float* __restrict__ x, const float* __restrict__ emb,
    const float* __restrict__ sq, int* __restrict__ idxp,
    float* __restrict__ counts, float* __restrict__ sumsq) {
  __shared__ float tile[256 * 60];
  __shared__ float lcnt[KC];
  __shared__ float lss[4];
  int t = threadIdx.x;
  long row0 = (long)blockIdx.x * 256;
  float acc[KC];
  #pragma unroll
  for (int k = 0; k < KC; k++) acc[k] = 0.f;
  float ss = 0.f;
  if (t < KC) lcnt[t] = 0.f;

  int col4 = t & 15, rq = t >> 4;
  for (int dg = 0; dg < D; dg += 56) {
    int CS = (D - dg) < 56 ? (D - dg) : 56;  // 56 or 44 (492 = 8*56 + 44)
    int nf4 = CS >> 2;                       // 14 or 11
    if (col4 < nf4) {
      #pragma unroll
      for (int j = 0; j < 16; j++) {
        int row = j * 16 + rq;
        float4 v = *(const float4*)&x[(row0 + row) * D + dg + col4 * 4];
        *(float4*)&tile[row * 60 + col4 * 4] = v;
      }
    }
    __syncthreads();
    for (int dd = 0; dd < CS; dd += 4) {
      float4 xv = *(const float4*)&tile[t * 60 + dd];
      ss = fmaf(xv.x, xv.x, ss); ss = fmaf(xv.y, xv.y, ss);
      ss = fmaf(xv.z, xv.z, ss); ss = fmaf(xv.w, xv.w, ss);
      #pragma unroll
      for (int k = 0; k < KC; k++) {
        // wave-uniform address -> s_load_dwordx4 expected
        float4 c = *(const float4*)&emb[k * D + dg + dd];
        acc[k] = fmaf(xv.x, c.x, acc[k]);
        acc[k] = fmaf(xv.y, c.y, acc[k]);
        acc[k] = fmaf(xv.z, c.z, acc[k]);
        acc[k] = fmaf(xv.w, c.w, acc[k]);
      }
    }
    __syncthreads();
  }
  // argmin_k (||e_k||^2 - 2 x.e_k)  -- ||x||^2 constant per row, dropped.
  float best = 3.4e38f; int bi = 0;
  #pragma unroll
  for (int k = 0; k < KC; k++) {
    float dk = sq[k] - 2.f * acc[k];
    if (dk < best) { best = dk; bi = k; }   // strict '<' keeps first min (jnp.argmin)
  }
  idxp[row0 + t] = bi;
  atomicAdd(&lcnt[bi], 1.f);
  #pragma unroll
  for (int off = 32; off; off >>= 1) ss += __shfl_down(ss, off, 64);
  int lane = t & 63, w = t >> 6;
  if (lane == 0) lss[w] = ss;
  __syncthreads();
  if (t == 0) atomicAdd(sumsq, lss[0] + lss[1] + lss[2] + lss[3]);
  if (t < KC) atomicAdd(&counts[t], lcnt[t]);
}

// ---------------------------------------------------------------- K2: dw segment-sum (one column half)
// Column-split so the per-block LDS dw tile is 40x246x4B = 39.4 KB (< 64 KB,
// 4 blocks/CU). Thread t owns columns {2t, 2t+1} -> non-atomic LDS RMW is
// race-free even across desynced waves. 8-row unroll keeps 8 loads in flight.
// Flush into one of 8 spread global partial copies (contention /8).
__global__ __launch_bounds__(128) void vq_dw(
    const float* __restrict__ x, const int* __restrict__ idxp,
    float* __restrict__ dwp, int c0) {
  __shared__ float ldw[KC * 246];
  int t = threadIdx.x;
  for (int i = t; i < KC * 246; i += 128) ldw[i] = 0.f;
  __syncthreads();
  long row0 = (long)blockIdx.x * 256;
  if (t < 123) {
    for (int r0 = 0; r0 < 256; r0 += 8) {
      int ks[8]; float2 xv[8];
      #pragma unroll
      for (int u = 0; u < 8; u++) ks[u] = idxp[row0 + r0 + u];  // uniform -> s_load
      #pragma unroll
      for (int u = 0; u < 8; u++)
        xv[u] = *(const float2*)&x[(row0 + r0 + u) * D + c0 + 2 * t];
      #pragma unroll
      for (int u = 0; u < 8; u++) {
        float2* p = (float2*)&ldw[ks[u] * 246 + 2 * t];
        float2 v = *p;
        v.x += xv[u].x; v.y += xv[u].y;
        *p = v;
      }
    }
  }
  __syncthreads();
  float* dst = dwp + (long)(blockIdx.x & 7) * (KC * D);
  for (int i = t; i < KC * 246; i += 128) {
    int k = i / 246;
    int col = i - k * 246;
    float v = ldw[i];
    if (v != 0.f) atomicAdd(&dst[k * D + c0 + col], v);
  }
}

// ---------------------------------------------------------------- K3: EMA update + closed-form loss
__global__ __launch_bounds__(256) void vq_final(
    const float* __restrict__ ema_w, const float* __restrict__ ema_cs,
    const float* __restrict__ counts, const float* __restrict__ dwp,
    const float* __restrict__ sumsq, float* __restrict__ out, long NDl) {
  __shared__ float lcs[KC], lcnt[KC];
  __shared__ float r1[4], r2[4];
  int t = threadIdx.x;
  if (t < KC) {
    float c = counts[t];
    lcnt[t] = c;
    lcs[t] = ema_cs[t] * DECAY + (1.f - DECAY) * c;
  }
  __syncthreads();
  if (t == 0) {
    float n = 0.f;
    for (int k = 0; k < KC; k++) n += lcs[k];
    for (int k = 0; k < KC; k++) lcs[k] = (lcs[k] + EPS) / (n + KC * EPS) * n;
  }
  __syncthreads();
  float t1 = 0.f, t2 = 0.f;
  for (int i = t; i < KC * D; i += 256) {
    float dwv = 0.f;
    #pragma unroll
    for (int c = 0; c < 8; c++) dwv += dwp[c * KC * D + i];
    int k = i / D;  // constant divisor -> magic mul
    float E = (DECAY * ema_w[i] + (1.f - DECAY) * dwv) / lcs[k];
    t1 = fmaf(lcnt[k] * E, E, t1);
    t2 = fmaf(E, dwv, t2);
  }
  #pragma unroll
  for (int off = 32; off; off >>= 1) {
    t1 += __shfl_down(t1, off, 64);
    t2 += __shfl_down(t2, off, 64);
  }
  int lane = t & 63, w = t >> 6;
  if (lane == 0) { r1[w] = t1; r2[w] = t2; }
  __syncthreads();
  if (t == 0) {
    double T1 = (double)r1[0] + r1[1] + r1[2] + r1[3];
    double T2 = (double)r2[0] + r2[1] + r2[2] + r2[3];
    double L = ((double)sumsq[0] - 2.0 * T2 + T1) / (double)NDl;
    out[0] = (float)L;
  }
}

// ---------------------------------------------------------------- launch
extern "C" void kernel_launch(void* const* d_in, const int* in_sizes, int n_in,
                              void* d_out, int out_size, void* d_ws, size_t ws_size,
                              hipStream_t stream) {
  const float* x = (const float*)d_in[0];
  const float* emb = (const float*)d_in[1];
  const float* ema_w = (const float*)d_in[2];
  const float* ema_cs = (const float*)d_in[3];
  float* out = (float*)d_out;
  long NDl = (long)in_sizes[0];
  int N = (int)(NDl / D);  // 262144

  char* ws = (char*)d_ws;
  float* sq = (float*)ws;                       // 40 floats
  float* counts = (float*)(ws + 256);           // 40 floats
  float* sumsq = (float*)(ws + 512);            // 1 float
  float* dwp = (float*)(ws + 1024);             // 8 * KC*D floats (spread partials)
  int* idxp = (int*)(ws + 1024 + 8 * KC * D * 4);  // N ints

  // zero counts + sumsq + dw partials (ws is poisoned 0xAA before every launch)
  hipMemsetAsync(ws + 256, 0, 768 + 8 * KC * D * 4, stream);

  vq_sqnorm<<<KC, 64, 0, stream>>>(emb, sq);
  vq_assign<<<N / 256, 256, 0, stream>>>(x, emb, sq, idxp, counts, sumsq);
  vq_dw<<<N / 256, 128, 0, stream>>>(x, idxp, dwp, 0);
  vq_dw<<<N / 256, 128, 0, stream>>>(x, idxp, dwp, 246);
  vq_final<<<1, 256, 0, stream>>>(ema_w, ema_cs, counts, dwp, sumsq, out, NDl);
}

// Round 2
// 1215.697 us; speedup vs baseline: 1.1790x; 1.1790x over previous
//
#include <hip/hip_runtime.h>

#define D 492
#define KC 40
#define DECAY 0.9f
#define EPS 1e-5f
#define PSPREAD 64   // dw partial copies

// ---------------------------------------------------------------- K0: ||e_k||^2
__global__ void vq_sqnorm(const float* __restrict__ emb, float* __restrict__ sq) {
  int k = blockIdx.x;
  int lane = threadIdx.x;
  float s = 0.f;
  for (int d = lane; d < D; d += 64) {
    float v = emb[k * D + d];
    s = fmaf(v, v, s);
  }
  #pragma unroll
  for (int off = 32; off; off >>= 1) s += __shfl_down(s, off, 64);
  if (lane == 0) sq[k] = s;
}

// ---------------------------------------------------------------- K1: assign
// 512 rows/block, 2 rows/thread (t, t+256). Codebook chunk staged in LDS ->
// wave-uniform broadcast ds_read_b128 (no L1 latency stalls). Per 4-col
// group: 320 FMAs vs 42 LDS reads -> VALU-bound. LDS ~61 KB -> 2 blocks/CU.
// CHUNK body: CS-col chunk at column DG. CS is a compile-time constant (24/12).
#define CHUNK_BODY(CS, DG)                                                     \
  {                                                                            \
    const int NF4 = (CS) / 4;                                                  \
    for (int j = t; j < 512 * NF4; j += 256) {                                 \
      int row = j / NF4;                                                       \
      int c4 = j - row * NF4;                                                  \
      *(float4*)&xt[row * 28 + c4 * 4] =                                       \
          *(const float4*)&x[(row0 + row) * D + (DG) + c4 * 4];                \
    }                                                                          \
    for (int i = t; i < KC * (CS); i += 256) {                                 \
      int k = i / (CS);                                                        \
      int c = i - k * (CS);                                                    \
      et[i] = emb[k * D + (DG) + c];                                           \
    }                                                                          \
    __syncthreads();                                                           \
    _Pragma("unroll")                                                          \
    for (int dd = 0; dd < (CS); dd += 4) {                                     \
      float4 xa = *(const float4*)&xt[t * 28 + dd];                            \
      float4 xb = *(const float4*)&xt[(t + 256) * 28 + dd];                    \
      ss = fmaf(xa.x, xa.x, ss); ss = fmaf(xa.y, xa.y, ss);                    \
      ss = fmaf(xa.z, xa.z, ss); ss = fmaf(xa.w, xa.w, ss);                    \
      ss = fmaf(xb.x, xb.x, ss); ss = fmaf(xb.y, xb.y, ss);                    \
      ss = fmaf(xb.z, xb.z, ss); ss = fmaf(xb.w, xb.w, ss);                    \
      _Pragma("unroll")                                                        \
      for (int k = 0; k < KC; k++) {                                           \
        float4 e = *(const float4*)&et[k * (CS) + dd];                         \
        acc0[k] = fmaf(xa.x, e.x, acc0[k]);                                    \
        acc0[k] = fmaf(xa.y, e.y, acc0[k]);                                    \
        acc0[k] = fmaf(xa.z, e.z, acc0[k]);                                    \
        acc0[k] = fmaf(xa.w, e.w, acc0[k]);                                    \
        acc1[k] = fmaf(xb.x, e.x, acc1[k]);                                    \
        acc1[k] = fmaf(xb.y, e.y, acc1[k]);                                    \
        acc1[k] = fmaf(xb.z, e.z, acc1[k]);                                    \
        acc1[k] = fmaf(xb.w, e.w, acc1[k]);                                    \
      }                                                                        \
    }                                                                          \
    __syncthreads();                                                           \
  }

__global__ __launch_bounds__(256) void vq_assign(
    const float* __restrict__ x, const float* __restrict__ emb,
    const float* __restrict__ sq, int* __restrict__ idxp,
    float* __restrict__ counts, float* __restrict__ sumsq) {
  __shared__ float xt[512 * 28];   // 57344 B (stride 28: 16B-aligned rows)
  __shared__ float et[KC * 24];    // 3840 B
  __shared__ float lcnt[KC];
  __shared__ float lss[4];
  int t = threadIdx.x;
  long row0 = (long)blockIdx.x * 512;
  float acc0[KC], acc1[KC];
  #pragma unroll
  for (int k = 0; k < KC; k++) { acc0[k] = 0.f; acc1[k] = 0.f; }
  float ss = 0.f;
  if (t < KC) lcnt[t] = 0.f;

  for (int dg = 0; dg < 480; dg += 24) CHUNK_BODY(24, dg)
  CHUNK_BODY(12, 480)   // 492 = 20*24 + 12

  // argmin_k (||e_k||^2 - 2 x.e_k); strict '<' keeps first min (jnp.argmin)
  float b0 = 3.4e38f, b1 = 3.4e38f; int i0 = 0, i1 = 0;
  #pragma unroll
  for (int k = 0; k < KC; k++) {
    float d0 = sq[k] - 2.f * acc0[k];
    float d1 = sq[k] - 2.f * acc1[k];
    if (d0 < b0) { b0 = d0; i0 = k; }
    if (d1 < b1) { b1 = d1; i1 = k; }
  }
  idxp[row0 + t] = i0;
  idxp[row0 + 256 + t] = i1;
  atomicAdd(&lcnt[i0], 1.f);
  atomicAdd(&lcnt[i1], 1.f);
  #pragma unroll
  for (int off = 32; off; off >>= 1) ss += __shfl_down(ss, off, 64);
  int lane = t & 63, w = t >> 6;
  if (lane == 0) lss[w] = ss;
  __syncthreads();
  if (t == 0) atomicAdd(sumsq, lss[0] + lss[1] + lss[2] + lss[3]);
  if (t < KC) atomicAdd(&counts[t], lcnt[t]);
}

// ---------------------------------------------------------------- K2: dw segment-sum
// Counting-sort the block's 512 rows by code, then per k-group accumulate in
// REGISTERS (thread owns cols 2t,2t+1; x rows read coalesced float2), one
// atomic flush per k-group into 1 of 64 spread partial copies.
__global__ __launch_bounds__(256) void vq_dw(
    const float* __restrict__ x, const int* __restrict__ idxp,
    float* __restrict__ dwp) {
  __shared__ int cnt[KC], base[KC], pos[KC];
  __shared__ unsigned short order[512];
  int t = threadIdx.x;
  long row0 = (long)blockIdx.x * 512;
  if (t < KC) cnt[t] = 0;
  __syncthreads();
  int k0 = idxp[row0 + t];
  int k1 = idxp[row0 + 256 + t];
  atomicAdd(&cnt[k0], 1);
  atomicAdd(&cnt[k1], 1);
  __syncthreads();
  if (t == 0) {
    int s = 0;
    for (int k = 0; k < KC; k++) { base[k] = s; pos[k] = s; s += cnt[k]; }
  }
  __syncthreads();
  int p0 = atomicAdd(&pos[k0], 1); order[p0] = (unsigned short)t;
  int p1 = atomicAdd(&pos[k1], 1); order[p1] = (unsigned short)(256 + t);
  __syncthreads();

  int c = 2 * t;
  bool act = c < D;  // 246 of 256 threads carry columns
  float* dst = dwp + (long)(blockIdx.x & (PSPREAD - 1)) * (KC * D);
  for (int k = 0; k < KC; k++) {
    int s = base[k], e = base[k] + cnt[k];
    if (s == e) continue;
    float ax = 0.f, ay = 0.f;
    int j = s;
    for (; j + 4 <= e; j += 4) {
      int r0 = order[j], r1 = order[j + 1], r2 = order[j + 2], r3 = order[j + 3];
      if (act) {
        float2 v0 = *(const float2*)&x[(row0 + r0) * D + c];
        float2 v1 = *(const float2*)&x[(row0 + r1) * D + c];
        float2 v2 = *(const float2*)&x[(row0 + r2) * D + c];
        float2 v3 = *(const float2*)&x[(row0 + r3) * D + c];
        ax += (v0.x + v1.x) + (v2.x + v3.x);
        ay += (v0.y + v1.y) + (v2.y + v3.y);
      }
    }
    for (; j < e; j++) {
      int r = order[j];
      if (act) {
        float2 v = *(const float2*)&x[(row0 + r) * D + c];
        ax += v.x; ay += v.y;
      }
    }
    if (act) {
      atomicAdd(&dst[k * D + c], ax);
      atomicAdd(&dst[k * D + c + 1], ay);
    }
  }
}

// ---------------------------------------------------------------- K3a: reduce 64 partials -> dw
__global__ __launch_bounds__(256) void vq_reduce(
    const float* __restrict__ dwp, float* __restrict__ dw) {
  int i = blockIdx.x * 256 + threadIdx.x;
  if (i >= KC * D) return;
  float s = 0.f;
  #pragma unroll 8
  for (int cpy = 0; cpy < PSPREAD; cpy++) s += dwp[cpy * (KC * D) + i];
  dw[i] = s;
}

// ---------------------------------------------------------------- K3b: EMA + closed-form loss
// loss*N*D = sumsq - 2*sum_k E_k.dw_k + sum_k counts_k*||E_k||^2
__global__ __launch_bounds__(256) void vq_final(
    const float* __restrict__ ema_w, const float* __restrict__ ema_cs,
    const float* __restrict__ counts, const float* __restrict__ dw,
    const float* __restrict__ sumsq, float* __restrict__ out, long NDl) {
  __shared__ float lcs[KC], lcnt[KC];
  __shared__ float r1[4], r2[4];
  int t = threadIdx.x;
  if (t < KC) {
    float c = counts[t];
    lcnt[t] = c;
    lcs[t] = ema_cs[t] * DECAY + (1.f - DECAY) * c;
  }
  __syncthreads();
  if (t == 0) {
    float n = 0.f;
    for (int k = 0; k < KC; k++) n += lcs[k];
    for (int k = 0; k < KC; k++) lcs[k] = (lcs[k] + EPS) / (n + KC * EPS) * n;
  }
  __syncthreads();
  float t1 = 0.f, t2 = 0.f;
  for (int i = t; i < KC * D; i += 256) {
    float dwv = dw[i];
    int k = i / D;  // constant divisor -> magic mul
    float E = (DECAY * ema_w[i] + (1.f - DECAY) * dwv) / lcs[k];
    t1 = fmaf(lcnt[k] * E, E, t1);
    t2 = fmaf(E, dwv, t2);
  }
  #pragma unroll
  for (int off = 32; off; off >>= 1) {
    t1 += __shfl_down(t1, off, 64);
    t2 += __shfl_down(t2, off, 64);
  }
  int lane = t & 63, w = t >> 6;
  if (lane == 0) { r1[w] = t1; r2[w] = t2; }
  __syncthreads();
  if (t == 0) {
    double T1 = (double)r1[0] + r1[1] + r1[2] + r1[3];
    double T2 = (double)r2[0] + r2[1] + r2[2] + r2[3];
    double L = ((double)sumsq[0] - 2.0 * T2 + T1) / (double)NDl;
    out[0] = (float)L;
  }
}

// ---------------------------------------------------------------- launch
extern "C" void kernel_launch(void* const* d_in, const int* in_sizes, int n_in,
                              void* d_out, int out_size, void* d_ws, size_t ws_size,
                              hipStream_t stream) {
  const float* x = (const float*)d_in[0];
  const float* emb = (const float*)d_in[1];
  const float* ema_w = (const float*)d_in[2];
  const float* ema_cs = (const float*)d_in[3];
  float* out = (float*)d_out;
  long NDl = (long)in_sizes[0];
  int N = (int)(NDl / D);  // 262144

  char* ws = (char*)d_ws;
  float* sq = (float*)ws;                         // 40 f
  float* counts = (float*)(ws + 256);             // 40 f
  float* sumsq = (float*)(ws + 512);              // 1 f
  float* dw = (float*)(ws + 1024);                // KC*D f (reduced)
  size_t part_off = 1024 + (size_t)KC * D * 4;    // 79744
  part_off = (part_off + 255) & ~(size_t)255;     // 79872
  float* dwp = (float*)(ws + part_off);           // PSPREAD * KC*D f
  size_t idx_off = part_off + (size_t)PSPREAD * KC * D * 4;
  int* idxp = (int*)(ws + idx_off);               // N ints

  // zero counts+sumsq and the dw partial copies (ws poisoned 0xAA each launch)
  hipMemsetAsync(ws + 256, 0, 768, stream);
  hipMemsetAsync(ws + part_off, 0, (size_t)PSPREAD * KC * D * 4, stream);

  vq_sqnorm<<<KC, 64, 0, stream>>>(emb, sq);
  vq_assign<<<N / 512, 256, 0, stream>>>(x, emb, sq, idxp, counts, sumsq);
  vq_dw<<<N / 512, 256, 0, stream>>>(x, idxp, dwp);
  vq_reduce<<<(KC * D + 255) / 256, 256, 0, stream>>>(dwp, dw);
  vq_final<<<1, 256, 0, stream>>>(ema_w, ema_cs, counts, dw, sumsq, out, NDl);
}

// Round 3
// 918.969 us; speedup vs baseline: 1.5597x; 1.3229x over previous
//
#include <hip/hip_runtime.h>

#define D 492
#define KC 40
#define DECAY 0.9f
#define EPS 1e-5f
#define PSPREAD 64   // dw partial copies

typedef __attribute__((ext_vector_type(8))) short bf16x8;
typedef __attribute__((ext_vector_type(4))) float f32x4;

// RNE fp32 -> bf16 (bit trick, no lib types)
__device__ __forceinline__ unsigned short f2bf(float f) {
  unsigned u = __float_as_uint(f);
  return (unsigned short)((u + 0x7fffu + ((u >> 16) & 1u)) >> 16);
}

// ---------------------------------------------------------------- K0: ||e_k||^2 (fp32)
__global__ void vq_sqnorm(const float* __restrict__ emb, float* __restrict__ sq) {
  int k = blockIdx.x;
  int lane = threadIdx.x;
  float s = 0.f;
  for (int d = lane; d < D; d += 64) {
    float v = emb[k * D + d];
    s = fmaf(v, v, s);
  }
  #pragma unroll
  for (int off = 32; off; off >>= 1) s += __shfl_down(s, off, 64);
  if (lane == 0) sq[k] = s;
}

// ---------------------------------------------------------------- K1: assign via bf16 MFMA
// 256 rows/block (grid 1024). C[256 x 48] = x_bf16 . emb_bf16^T via
// mfma_f32_16x16x32_bf16: wave w owns rows w*64..+63 (4 M-tiles x 3 N-tiles,
// 48 acc VGPRs). x fp32 streamed -> RNE bf16 -> LDS (stride 40 bf16 = 80 B:
// 16B-aligned, exact 2-way bank alias = free). Codebook chunk re-staged per
// k-step (L2-resident, ~80 MB total = free). Fused: sumsq (fp32, from the
// staging registers) + counts. Epilogue: per-row argmin over 40 codes from
// the C-layout (col=lane&15, row=quad*4+reg), 16-lane xor-shuffle reduce.
__global__ __launch_bounds__(256, 3) void vq_assign(
    const float* __restrict__ x, const float* __restrict__ emb,
    const float* __restrict__ sq, int* __restrict__ idxp,
    float* __restrict__ counts, float* __restrict__ sumsq) {
  __shared__ unsigned short As[256 * 40];  // 20.0 KB  (32 k used, 8 pad)
  __shared__ unsigned short Bs[48 * 40];   //  3.75 KB
  __shared__ float sq_s[KC];
  __shared__ float lcnt[KC];
  __shared__ float lss[4];
  int t = threadIdx.x;
  long row0 = (long)blockIdx.x * 256;
  if (t < KC) { sq_s[t] = sq[t]; lcnt[t] = 0.f; }
  float ss = 0.f;
  f32x4 acc[4][3];
  #pragma unroll
  for (int m = 0; m < 4; m++)
    #pragma unroll
    for (int n = 0; n < 3; n++) acc[m][n] = (f32x4){0.f, 0.f, 0.f, 0.f};

  int w = t >> 6, L = t & 63;
  int lm = L & 15, kq = L >> 4;

  for (int step = 0; step < 16; step++) {  // K padded 492 -> 512
    int kbase = step * 32;
    // ---- stage A (x rows): j -> (r = j>>3, c4 = j&7); wave = 8 rows x 128 B
    #pragma unroll
    for (int i = 0; i < 8; i++) {
      int j = t + i * 256;
      int r = j >> 3, c4 = j & 7;
      int col = kbase + c4 * 4;
      float4 v = make_float4(0.f, 0.f, 0.f, 0.f);
      if (col < D) v = *(const float4*)&x[(row0 + r) * D + col];
      ss = fmaf(v.x, v.x, fmaf(v.y, v.y, fmaf(v.z, v.z, fmaf(v.w, v.w, ss))));
      ushort4 u = { f2bf(v.x), f2bf(v.y), f2bf(v.z), f2bf(v.w) };
      *(ushort4*)&As[r * 40 + c4 * 4] = u;
    }
    // ---- stage B (codebook chunk, zero-padded codes 40..47)
    {
      int n = t >> 3, c4 = t & 7;
      int col = kbase + c4 * 4;
      float4 v = make_float4(0.f, 0.f, 0.f, 0.f);
      if (n < KC && col < D) v = *(const float4*)&emb[n * D + col];
      ushort4 u = { f2bf(v.x), f2bf(v.y), f2bf(v.z), f2bf(v.w) };
      *(ushort4*)&Bs[n * 40 + c4 * 4] = u;
      if (t < 128) {
        int j = t + 256;
        n = j >> 3; c4 = j & 7;
        col = kbase + c4 * 4;
        v = make_float4(0.f, 0.f, 0.f, 0.f);
        if (n < KC && col < D) v = *(const float4*)&emb[n * D + col];
        ushort4 u2 = { f2bf(v.x), f2bf(v.y), f2bf(v.z), f2bf(v.w) };
        *(ushort4*)&Bs[n * 40 + c4 * 4] = u2;
      }
    }
    __syncthreads();
    // ---- fragments + 12 MFMAs
    bf16x8 a[4], b[3];
    #pragma unroll
    for (int m = 0; m < 4; m++)
      a[m] = *(const bf16x8*)&As[(w * 64 + m * 16 + lm) * 40 + kq * 8];
    #pragma unroll
    for (int n = 0; n < 3; n++)
      b[n] = *(const bf16x8*)&Bs[(n * 16 + lm) * 40 + kq * 8];
    #pragma unroll
    for (int m = 0; m < 4; m++)
      #pragma unroll
      for (int n = 0; n < 3; n++)
        acc[m][n] = __builtin_amdgcn_mfma_f32_16x16x32_bf16(a[m], b[n], acc[m][n], 0, 0, 0);
    __syncthreads();
  }

  // ---- epilogue: per-row argmin of sq[k] - 2*dot (||x||^2 dropped)
  #pragma unroll
  for (int m = 0; m < 4; m++) {
    #pragma unroll
    for (int reg = 0; reg < 4; reg++) {
      float best = 3.4e38f; int bi = 0;
      #pragma unroll
      for (int n = 0; n < 3; n++) {
        int col = n * 16 + lm;
        if (col < KC) {
          float v = sq_s[col] - 2.f * acc[m][n][reg];
          if (v < best || (v == best && col < bi)) { best = v; bi = col; }
        }
      }
      #pragma unroll
      for (int off = 1; off < 16; off <<= 1) {
        float ov = __shfl_xor(best, off, 64);
        int oi = __shfl_xor(bi, off, 64);
        if (ov < best || (ov == best && oi < bi)) { best = ov; bi = oi; }
      }
      if (lm == 0) {
        int r = w * 64 + m * 16 + kq * 4 + reg;
        idxp[row0 + r] = bi;
        atomicAdd(&lcnt[bi], 1.f);
      }
    }
  }
  // ---- sumsq + counts flush
  #pragma unroll
  for (int off = 32; off; off >>= 1) ss += __shfl_down(ss, off, 64);
  if (L == 0) lss[w] = ss;
  __syncthreads();
  if (t == 0) atomicAdd(sumsq, lss[0] + lss[1] + lss[2] + lss[3]);
  if (t < KC) atomicAdd(&counts[t], lcnt[t]);
}

// ---------------------------------------------------------------- K2: dw segment-sum
// 512 rows/block (grid 512), 128 threads; thread t owns cols 4t..4t+3
// (t<123). Counting-sort rows by code into packed order[] (r | k<<9), then
// stream ALL rows as one flat list: 8-row prefetch double-buffer, register
// float4 accumulator, wave-uniform flush-on-k-change (one atomic burst per
// k-group) into 1 of 64 spread partial copies.
__global__ __launch_bounds__(128) void vq_dw(
    const float* __restrict__ x, const int* __restrict__ idxp,
    float* __restrict__ dwp) {
  __shared__ int cnt[KC], base[KC], pos[KC];
  __shared__ unsigned short order[512];
  int t = threadIdx.x;
  long row0 = (long)blockIdx.x * 512;
  if (t < KC) cnt[t] = 0;
  __syncthreads();
  int myk[4];
  #pragma unroll
  for (int u = 0; u < 4; u++) {
    myk[u] = idxp[row0 + t + u * 128];
    atomicAdd(&cnt[myk[u]], 1);
  }
  __syncthreads();
  if (t == 0) {
    int s = 0;
    for (int k = 0; k < KC; k++) { base[k] = s; pos[k] = s; s += cnt[k]; }
  }
  __syncthreads();
  #pragma unroll
  for (int u = 0; u < 4; u++) {
    int p = atomicAdd(&pos[myk[u]], 1);
    order[p] = (unsigned short)((t + u * 128) | (myk[u] << 9));
  }
  __syncthreads();

  int c = 4 * t;
  bool act = c < D;  // 123 of 128 threads carry columns
  float* dst = dwp + (long)(blockIdx.x & (PSPREAD - 1)) * (KC * D);
  float4 a = make_float4(0.f, 0.f, 0.f, 0.f);
  int kcur = -1;

  int pk[8], pk2[8];
  float4 v[8], v2[8];
  #pragma unroll
  for (int u = 0; u < 8; u++) pk[u] = order[u];
  #pragma unroll
  for (int u = 0; u < 8; u++)
    v[u] = act ? *(const float4*)&x[(row0 + (pk[u] & 511)) * D + c]
               : make_float4(0.f, 0.f, 0.f, 0.f);

  for (int j0 = 0; j0 < 512; j0 += 8) {
    if (j0 + 8 < 512) {
      #pragma unroll
      for (int u = 0; u < 8; u++) pk2[u] = order[j0 + 8 + u];
      #pragma unroll
      for (int u = 0; u < 8; u++)
        v2[u] = act ? *(const float4*)&x[(row0 + (pk2[u] & 511)) * D + c]
                    : make_float4(0.f, 0.f, 0.f, 0.f);
    }
    #pragma unroll
    for (int u = 0; u < 8; u++) {
      int k = pk[u] >> 9;           // wave-uniform
      if (k != kcur) {              // uniform branch, ~40 flushes per block
        if (kcur >= 0 && act) {
          atomicAdd(&dst[kcur * D + c], a.x);
          atomicAdd(&dst[kcur * D + c + 1], a.y);
          atomicAdd(&dst[kcur * D + c + 2], a.z);
          atomicAdd(&dst[kcur * D + c + 3], a.w);
        }
        a = v[u]; kcur = k;
      } else {
        a.x += v[u].x; a.y += v[u].y; a.z += v[u].z; a.w += v[u].w;
      }
    }
    #pragma unroll
    for (int u = 0; u < 8; u++) { pk[u] = pk2[u]; v[u] = v2[u]; }
  }
  if (kcur >= 0 && act) {
    atomicAdd(&dst[kcur * D + c], a.x);
    atomicAdd(&dst[kcur * D + c + 1], a.y);
    atomicAdd(&dst[kcur * D + c + 2], a.z);
    atomicAdd(&dst[kcur * D + c + 3], a.w);
  }
}

// ---------------------------------------------------------------- K3a: reduce 64 partials -> dw
__global__ __launch_bounds__(256) void vq_reduce(
    const float* __restrict__ dwp, float* __restrict__ dw) {
  int i = blockIdx.x * 256 + threadIdx.x;
  if (i >= KC * D) return;
  float s = 0.f;
  #pragma unroll 8
  for (int cpy = 0; cpy < PSPREAD; cpy++) s += dwp[cpy * (KC * D) + i];
  dw[i] = s;
}

// ---------------------------------------------------------------- K3b: EMA + closed-form loss
// loss*N*D = sumsq - 2*sum_k E_k.dw_k + sum_k counts_k*||E_k||^2
__global__ __launch_bounds__(256) void vq_final(
    const float* __restrict__ ema_w, const float* __restrict__ ema_cs,
    const float* __restrict__ counts, const float* __restrict__ dw,
    const float* __restrict__ sumsq, float* __restrict__ out, long NDl) {
  __shared__ float lcs[KC], lcnt[KC];
  __shared__ float r1[4], r2[4];
  int t = threadIdx.x;
  if (t < KC) {
    float c = counts[t];
    lcnt[t] = c;
    lcs[t] = ema_cs[t] * DECAY + (1.f - DECAY) * c;
  }
  __syncthreads();
  if (t == 0) {
    float n = 0.f;
    for (int k = 0; k < KC; k++) n += lcs[k];
    for (int k = 0; k < KC; k++) lcs[k] = (lcs[k] + EPS) / (n + KC * EPS) * n;
  }
  __syncthreads();
  float t1 = 0.f, t2 = 0.f;
  for (int i = t; i < KC * D; i += 256) {
    float dwv = dw[i];
    int k = i / D;
    float E = (DECAY * ema_w[i] + (1.f - DECAY) * dwv) / lcs[k];
    t1 = fmaf(lcnt[k] * E, E, t1);
    t2 = fmaf(E, dwv, t2);
  }
  #pragma unroll
  for (int off = 32; off; off >>= 1) {
    t1 += __shfl_down(t1, off, 64);
    t2 += __shfl_down(t2, off, 64);
  }
  int lane = t & 63, w = t >> 6;
  if (lane == 0) { r1[w] = t1; r2[w] = t2; }
  __syncthreads();
  if (t == 0) {
    double T1 = (double)r1[0] + r1[1] + r1[2] + r1[3];
    double T2 = (double)r2[0] + r2[1] + r2[2] + r2[3];
    double L = ((double)sumsq[0] - 2.0 * T2 + T1) / (double)NDl;
    out[0] = (float)L;
  }
}

// ---------------------------------------------------------------- launch
extern "C" void kernel_launch(void* const* d_in, const int* in_sizes, int n_in,
                              void* d_out, int out_size, void* d_ws, size_t ws_size,
                              hipStream_t stream) {
  const float* x = (const float*)d_in[0];
  const float* emb = (const float*)d_in[1];
  const float* ema_w = (const float*)d_in[2];
  const float* ema_cs = (const float*)d_in[3];
  float* out = (float*)d_out;
  long NDl = (long)in_sizes[0];
  int N = (int)(NDl / D);  // 262144

  char* ws = (char*)d_ws;
  float* sq = (float*)ws;                         // 40 f
  float* counts = (float*)(ws + 256);             // 40 f
  float* sumsq = (float*)(ws + 512);              // 1 f
  float* dw = (float*)(ws + 1024);                // KC*D f (reduced)
  size_t part_off = 1024 + (size_t)KC * D * 4;
  part_off = (part_off + 255) & ~(size_t)255;
  float* dwp = (float*)(ws + part_off);           // PSPREAD * KC*D f
  size_t idx_off = part_off + (size_t)PSPREAD * KC * D * 4;
  int* idxp = (int*)(ws + idx_off);               // N ints

  hipMemsetAsync(ws + 256, 0, 768, stream);
  hipMemsetAsync(ws + part_off, 0, (size_t)PSPREAD * KC * D * 4, stream);

  vq_sqnorm<<<KC, 64, 0, stream>>>(emb, sq);
  vq_assign<<<N / 256, 256, 0, stream>>>(x, emb, sq, idxp, counts, sumsq);
  vq_dw<<<N / 512, 128, 0, stream>>>(x, idxp, dwp);
  vq_reduce<<<(KC * D + 255) / 256, 256, 0, stream>>>(dwp, dw);
  vq_final<<<1, 256, 0, stream>>>(ema_w, ema_cs, counts, dw, sumsq, out, NDl);
}